// Round 2
// baseline (598.290 us; speedup 1.0000x reference)
//
#include <hip/hip_runtime.h>

// EGNN fused layer, MI355X gfx950. Round 2.
// Key changes vs R1 (VALU-bound, 58% VALUBusy, MfmaUtil 10%):
//  - edge-MLP layer 2 folded into Wn1/Wc1:  e@Wn1[128:160] == s@(We2@Wn1[128:160])
//    -> in-loop edge work is just s = silu(d*We1+be1), 8 vals/thread
//  - h pre-converted to bf16 in ws: staging = ushort8 load + b128 LDS write
//  - coord path: in-register silu*Wc2 + shfl_xor value-folding butterfly
//    (no second LDS round trip, 2 fewer barriers)
//  - node path: GEMM1 col map col=w*32+l15*2+nt -> paired b32 hl writes
//  - silu via v_rcp (1ulp) instead of precise fp32 division
//  - 3 blocks/CU (LDS ~41 KB, __launch_bounds__(256,3))

#define NN 50000
#define NE 800000
#define NDIM 64
#define HDIM 128
#define NTILES (NE / 64)      // 12500 exact
#define MSTRIDE 168           // m_input LDS row stride (ushort): 160 + 8 pad
#define HSTRIDE 136           // hidden LDS row stride (ushort): 128 + 8 pad
#define NH (NN * NDIM)
#define NX (NN * 3)

// ws layout (bytes)
#define WS_HBF    0           // ushort[NN*64]  = 6,400,000 B
#define WS_WN1P   6400000     // ushort[160*128] = 40,960 B (fused, bf16)
#define WS_WC1P   6440960     // ushort[160*128]
#define WS_BN1P   6481920     // float[128]
#define WS_BC1P   6482432     // float[128]

typedef __bf16 bf16x8 __attribute__((ext_vector_type(8)));
typedef float f32x4 __attribute__((ext_vector_type(4)));
typedef unsigned short ushort8 __attribute__((ext_vector_type(8)));
typedef unsigned short ushort4v __attribute__((ext_vector_type(4)));

__device__ __forceinline__ unsigned short f2bf(float f) {
    union { float f; unsigned int u; } c; c.f = f;
    unsigned int r = c.u + 0x7fffu + ((c.u >> 16) & 1u);   // RNE
    return (unsigned short)(r >> 16);
}
__device__ __forceinline__ unsigned int pk2bf(float a, float b) {
    return (unsigned int)f2bf(a) | ((unsigned int)f2bf(b) << 16);
}
__device__ __forceinline__ float silu(float v) {
    // v * sigmoid(v); rcp approx (1 ulp) instead of precise division
    return v * __builtin_amdgcn_rcpf(1.0f + __expf(-v));
}
__device__ __forceinline__ bf16x8 ld_frag(const unsigned short* p) {
    union { ushort8 u; bf16x8 v; } c;
    c.u = *(const ushort8*)p;
    return c.v;
}
__device__ __forceinline__ bf16x8 mk_frag(const unsigned short* u) {
    union { ushort8 uu; bf16x8 v; } c;
#pragma unroll
    for (int j = 0; j < 8; ++j) c.uu[j] = u[j];
    return c.v;
}

__global__ void init_out(const float* __restrict__ h, const float* __restrict__ x,
                         float* __restrict__ out) {
    int i = blockIdx.x * 256 + threadIdx.x;
    if (i < NH) out[i] = h[i];
    else if (i < NH + NX) out[i] = x[i - NH];
}

// h (f32) -> bf16 in ws. NH divisible by 4.
__global__ void prep_h(const float* __restrict__ h, unsigned short* __restrict__ hbf) {
    int i = (blockIdx.x * 256 + threadIdx.x) * 4;
    if (i < NH) {
        float4 v = *(const float4*)(h + i);
        ushort4v u = { f2bf(v.x), f2bf(v.y), f2bf(v.z), f2bf(v.w) };
        *(ushort4v*)(hbf + i) = u;
    }
}

// Fused weights: Wn1'[k][n] = k<128 ? Wn1[k][n] : sum_j We2[k-128][j]*Wn1[128+j][n]
// bn1'[n] = bn1[n] + sum_j be2[j]*Wn1[128+j][n]   (same for c path)
__global__ void prep_w(const float* __restrict__ We2, const float* __restrict__ be2,
                       const float* __restrict__ Wn1, const float* __restrict__ bn1,
                       const float* __restrict__ Wc1, const float* __restrict__ bc1,
                       unsigned short* __restrict__ wn1p, unsigned short* __restrict__ wc1p,
                       float* __restrict__ bn1p, float* __restrict__ bc1p) {
    int idx = blockIdx.x * 256 + threadIdx.x;
    if (idx >= 160 * 128) return;
    int k = idx >> 7, n = idx & 127;
    float vn, vc;
    if (k < 128) {
        vn = Wn1[k * HDIM + n];
        vc = Wc1[k * HDIM + n];
    } else {
        int i = k - 128;
        float sn = 0.0f, sc = 0.0f;
        for (int j = 0; j < 32; ++j) {
            float w = We2[i * 32 + j];
            sn += w * Wn1[(128 + j) * HDIM + n];
            sc += w * Wc1[(128 + j) * HDIM + n];
        }
        vn = sn; vc = sc;
    }
    wn1p[idx] = f2bf(vn);
    wc1p[idx] = f2bf(vc);
    if (idx < 128) {
        float sn = bn1[idx], sc = bc1[idx];
        for (int j = 0; j < 32; ++j) {
            sn += be2[j] * Wn1[(128 + j) * HDIM + idx];
            sc += be2[j] * Wc1[(128 + j) * HDIM + idx];
        }
        bn1p[idx] = sn;
        bc1p[idx] = sc;
    }
}

__global__ __launch_bounds__(256, 3) void egnn_edges(
    const unsigned short* __restrict__ hbf, const float* __restrict__ x,
    const int* __restrict__ srcg, const int* __restrict__ dstg,
    const float* __restrict__ dist,
    const float* __restrict__ We1, const float* __restrict__ be1,
    const unsigned short* __restrict__ wn1p, const float* __restrict__ bn1p,
    const float* __restrict__ Wn2, const float* __restrict__ bn2,
    const unsigned short* __restrict__ wc1p, const float* __restrict__ bc1p,
    const float* __restrict__ Wc2,
    float* __restrict__ outh, float* __restrict__ outx) {

    __shared__ __align__(16) unsigned short mlds[64 * MSTRIDE];  // 21.5 KB
    __shared__ __align__(16) unsigned short hl[64 * HSTRIDE];    // 17.4 KB
    __shared__ int src_l[64];
    __shared__ int dst_l[64];
    __shared__ float dist_l[64];
    __shared__ float part_l[256];

    const int tid  = threadIdx.x;
    const int w    = tid >> 6;
    const int lane = tid & 63;
    const int l15  = lane & 15;
    const int quad = lane >> 4;

    // ---- one-time: B-fragments to registers ----
    // GEMM1 col map: col = w*32 + l15*2 + nt  (adjacent col pair per lane)
    bf16x8 wn1f[5][2], wc1f[5][2];
#pragma unroll
    for (int kc = 0; kc < 5; ++kc) {
#pragma unroll
        for (int nt = 0; nt < 2; ++nt) {
            unsigned short un[8], uc[8];
            const int n = w * 32 + l15 * 2 + nt;
#pragma unroll
            for (int j = 0; j < 8; ++j) {
                const int k = kc * 32 + quad * 8 + j;
                un[j] = wn1p[k * HDIM + n];
                uc[j] = wc1p[k * HDIM + n];
            }
            wn1f[kc][nt] = mk_frag(un);
            wc1f[kc][nt] = mk_frag(uc);
        }
    }
    // GEMM2: out col = w*16 + l15
    bf16x8 wn2f[4];
#pragma unroll
    for (int kc = 0; kc < 4; ++kc) {
        unsigned short u[8];
        const int n = w * 16 + l15;
#pragma unroll
        for (int j = 0; j < 8; ++j) {
            const int k = kc * 32 + quad * 8 + j;
            u[j] = f2bf(Wn2[k * NDIM + n]);
        }
        wn2f[kc] = mk_frag(u);
    }
    const float biasN0 = bn1p[w * 32 + l15 * 2];
    const float biasN1 = bn1p[w * 32 + l15 * 2 + 1];
    const float biasC0 = bc1p[w * 32 + l15 * 2];
    const float biasC1 = bc1p[w * 32 + l15 * 2 + 1];
    const float bias2v = bn2[w * 16 + l15];
    const float wc2a = Wc2[w * 32 + l15 * 2];
    const float wc2b = Wc2[w * 32 + l15 * 2 + 1];

    for (int tile = blockIdx.x; tile < NTILES; tile += gridDim.x) {
        __syncthreads();   // LDS reuse guard

        if (tid < 64) {
            const int e = tile * 64 + tid;
            src_l[tid] = srcg[e];
            dst_l[tid] = dstg[e];
            dist_l[tid] = dist[e];
        }
        __syncthreads();

        // ---- stage m_input = [h_src(64) | h_dst(64) | s(32)] bf16 ----
        {
            const int c8 = tid & 7, sub = tid >> 3;   // 8 cols x 32 rows
#pragma unroll
            for (int it = 0; it < 2; ++it) {
                const int el = sub + it * 32;
                const ushort8 hs = *(const ushort8*)(hbf + (size_t)src_l[el] * NDIM + c8 * 8);
                const ushort8 hd = *(const ushort8*)(hbf + (size_t)dst_l[el] * NDIM + c8 * 8);
                *(ushort8*)&mlds[el * MSTRIDE + c8 * 8] = hs;
                *(ushort8*)&mlds[el * MSTRIDE + 64 + c8 * 8] = hd;
            }
        }
        // s = silu(d*We1 + be1): 8 vals/thread, wave w covers k in [w*8, w*8+8)
        {
            const float dv = dist_l[lane];
            ushort8 su;
#pragma unroll
            for (int j = 0; j < 8; ++j) {
                const int k = w * 8 + j;
                su[j] = f2bf(silu(fmaf(dv, We1[k], be1[k])));
            }
            *(ushort8*)&mlds[lane * MSTRIDE + 128 + w * 8] = su;
        }
        __syncthreads();

        // ---- GEMM1: [64x160] @ {Wn1', Wc1'} -> hidden [64x128] each ----
        f32x4 accN[4][2], accC[4][2];
#pragma unroll
        for (int mt = 0; mt < 4; ++mt) {
            accN[mt][0] = (f32x4){biasN0, biasN0, biasN0, biasN0};
            accN[mt][1] = (f32x4){biasN1, biasN1, biasN1, biasN1};
            accC[mt][0] = (f32x4){biasC0, biasC0, biasC0, biasC0};
            accC[mt][1] = (f32x4){biasC1, biasC1, biasC1, biasC1};
        }
#pragma unroll
        for (int kc = 0; kc < 5; ++kc) {
            bf16x8 af[4];
#pragma unroll
            for (int mt = 0; mt < 4; ++mt)
                af[mt] = ld_frag(&mlds[(mt * 16 + l15) * MSTRIDE + kc * 32 + quad * 8]);
#pragma unroll
            for (int mt = 0; mt < 4; ++mt) {
#pragma unroll
                for (int nt = 0; nt < 2; ++nt) {
                    accN[mt][nt] = __builtin_amdgcn_mfma_f32_16x16x32_bf16(
                        af[mt], wn1f[kc][nt], accN[mt][nt], 0, 0, 0);
                    accC[mt][nt] = __builtin_amdgcn_mfma_f32_16x16x32_bf16(
                        af[mt], wc1f[kc][nt], accC[mt][nt], 0, 0, 0);
                }
            }
        }

        // ---- node path: silu -> paired b32 writes into hl (A-layout by col) ----
#pragma unroll
        for (int mt = 0; mt < 4; ++mt) {
#pragma unroll
            for (int r = 0; r < 4; ++r) {
                const int row = mt * 16 + quad * 4 + r;
                *(unsigned int*)&hl[row * HSTRIDE + w * 32 + l15 * 2] =
                    pk2bf(silu(accN[mt][0][r]), silu(accN[mt][1][r]));
            }
        }
        __syncthreads();

        // ---- GEMM2 node: [64x128] @ Wn2 -> m [64x64], atomic scatter ----
        f32x4 acc2[4];
#pragma unroll
        for (int mt = 0; mt < 4; ++mt) acc2[mt] = (f32x4){bias2v, bias2v, bias2v, bias2v};
#pragma unroll
        for (int kc = 0; kc < 4; ++kc) {
#pragma unroll
            for (int mt = 0; mt < 4; ++mt) {
                bf16x8 a2 = ld_frag(&hl[(mt * 16 + l15) * HSTRIDE + kc * 32 + quad * 8]);
                acc2[mt] = __builtin_amdgcn_mfma_f32_16x16x32_bf16(a2, wn2f[kc], acc2[mt], 0, 0, 0);
            }
        }
#pragma unroll
        for (int mt = 0; mt < 4; ++mt) {
#pragma unroll
            for (int r = 0; r < 4; ++r) {
                const int el = mt * 16 + quad * 4 + r;
                atomicAdd(outh + (size_t)dst_l[el] * NDIM + w * 16 + l15, acc2[mt][r]);
            }
        }

        // ---- coord path: in-register silu*Wc2 + shfl_xor fold (no LDS trip) ----
        {
            float vals[16];
#pragma unroll
            for (int mt = 0; mt < 4; ++mt)
#pragma unroll
                for (int r = 0; r < 4; ++r)
                    vals[mt * 4 + r] = silu(accC[mt][0][r]) * wc2a +
                                       silu(accC[mt][1][r]) * wc2b;
            // value-folding butterfly across the 16 lanes of this quad;
            // lane l15 ends holding the full sum for value index l15.
#pragma unroll
            for (int m = 8; m >= 1; m >>= 1) {
                const bool up = (l15 & m) != 0;
#pragma unroll
                for (int j = 0; j < 8; ++j) {
                    if (j < m) {
                        float send = up ? vals[j] : vals[j + m];
                        float recv = __shfl_xor(send, m, 64);
                        vals[j] = (up ? vals[j + m] : vals[j]) + recv;
                    }
                }
            }
            // value index i = mt*4 + r -> edge = mt*16 + quad*4 + r
            const int edge = ((l15 >> 2) << 4) + (quad << 2) + (l15 & 3);
            part_l[w * 64 + edge] = vals[0];
        }
        __syncthreads();

        if (tid < 64) {
            const float cw = part_l[tid] + part_l[64 + tid] + part_l[128 + tid] + part_l[192 + tid];
            const int sn = src_l[tid], dn = dst_l[tid];
            const float dx = x[sn * 3 + 0] - x[dn * 3 + 0];
            const float dy = x[sn * 3 + 1] - x[dn * 3 + 1];
            const float dz = x[sn * 3 + 2] - x[dn * 3 + 2];
            float len = sqrtf(dx * dx + dy * dy + dz * dz);
            len = fmaxf(len, 1e-8f);
            const float f = cw / len;
            atomicAdd(outx + (size_t)dn * 3 + 0, f * dx);
            atomicAdd(outx + (size_t)dn * 3 + 1, f * dy);
            atomicAdd(outx + (size_t)dn * 3 + 2, f * dz);
        }
    }
}

extern "C" void kernel_launch(void* const* d_in, const int* in_sizes, int n_in,
                              void* d_out, int out_size, void* d_ws, size_t ws_size,
                              hipStream_t stream) {
    const float* h    = (const float*)d_in[0];
    const float* x    = (const float*)d_in[1];
    const int*   ei   = (const int*)d_in[2];
    const float* dist = (const float*)d_in[3];
    const float* We1  = (const float*)d_in[4];
    const float* be1  = (const float*)d_in[5];
    const float* We2  = (const float*)d_in[6];
    const float* be2  = (const float*)d_in[7];
    const float* Wn1  = (const float*)d_in[8];
    const float* bn1  = (const float*)d_in[9];
    const float* Wn2  = (const float*)d_in[10];
    const float* bn2  = (const float*)d_in[11];
    const float* Wc1  = (const float*)d_in[12];
    const float* bc1  = (const float*)d_in[13];
    const float* Wc2  = (const float*)d_in[14];

    unsigned short* hbf  = (unsigned short*)((char*)d_ws + WS_HBF);
    unsigned short* wn1p = (unsigned short*)((char*)d_ws + WS_WN1P);
    unsigned short* wc1p = (unsigned short*)((char*)d_ws + WS_WC1P);
    float* bn1p = (float*)((char*)d_ws + WS_BN1P);
    float* bc1p = (float*)((char*)d_ws + WS_BC1P);

    float* outh = (float*)d_out;
    float* outx = outh + (size_t)NH;

    prep_h<<<(NH / 4 + 255) / 256, 256, 0, stream>>>(h, hbf);
    prep_w<<<(160 * 128 + 255) / 256, 256, 0, stream>>>(We2, be2, Wn1, bn1, Wc1, bc1,
                                                        wn1p, wc1p, bn1p, bc1p);
    init_out<<<(NH + NX + 255) / 256, 256, 0, stream>>>(h, x, (float*)d_out);
    egnn_edges<<<1024, 256, 0, stream>>>(hbf, x, ei, ei + NE, dist,
                                         We1, be1, wn1p, bn1p,
                                         Wn2, bn2, wc1p, bc1p, Wc2,
                                         outh, outx);
}

// Round 3
// 450.052 us; speedup vs baseline: 1.3294x; 1.3294x over previous
//
#include <hip/hip_runtime.h>

// EGNN fused layer, MI355X gfx950. Round 3.
// R2 post-mortem: __launch_bounds__(256,3) capped the unified VGPR+AGPR budget
// at ~170/thread; the 96-VGPR weight-fragment set spilled to scratch and was
// reloaded every tile (~1 GB HBM fetch, matches FETCH_SIZE 967 MB). Fix:
// restore (256,2) budget so weights stay resident. Grid 512 (=2 blocks/CU max).
// All R2 VALU cuts kept:
//  - edge-MLP layer 2 folded into Wn1/Wc1 (prep_w): in-loop edge work = 8 silu
//  - h pre-converted to bf16 (prep_h): staging = ushort8 load + b128 LDS write
//  - coord path: in-register silu*Wc2 + shfl_xor fold, no 2nd LDS round trip
//  - node path: paired b32 hl writes (col = w*32 + l15*2 + nt)
//  - silu via v_rcp

#define NN 50000
#define NE 800000
#define NDIM 64
#define HDIM 128
#define NTILES (NE / 64)      // 12500 exact
#define MSTRIDE 168           // m_input LDS row stride (ushort): 160 + 8 pad
#define HSTRIDE 136           // hidden LDS row stride (ushort): 128 + 8 pad
#define NH (NN * NDIM)
#define NX (NN * 3)

// ws layout (bytes)
#define WS_HBF    0           // ushort[NN*64]  = 6,400,000 B
#define WS_WN1P   6400000     // ushort[160*128] = 40,960 B (fused, bf16)
#define WS_WC1P   6440960     // ushort[160*128]
#define WS_BN1P   6481920     // float[128]
#define WS_BC1P   6482432     // float[128]

typedef __bf16 bf16x8 __attribute__((ext_vector_type(8)));
typedef float f32x4 __attribute__((ext_vector_type(4)));
typedef unsigned short ushort8 __attribute__((ext_vector_type(8)));
typedef unsigned short ushort4v __attribute__((ext_vector_type(4)));

__device__ __forceinline__ unsigned short f2bf(float f) {
    union { float f; unsigned int u; } c; c.f = f;
    unsigned int r = c.u + 0x7fffu + ((c.u >> 16) & 1u);   // RNE
    return (unsigned short)(r >> 16);
}
__device__ __forceinline__ unsigned int pk2bf(float a, float b) {
    return (unsigned int)f2bf(a) | ((unsigned int)f2bf(b) << 16);
}
__device__ __forceinline__ float silu(float v) {
    return v * __builtin_amdgcn_rcpf(1.0f + __expf(-v));
}
__device__ __forceinline__ bf16x8 ld_frag(const unsigned short* p) {
    union { ushort8 u; bf16x8 v; } c;
    c.u = *(const ushort8*)p;
    return c.v;
}
__device__ __forceinline__ bf16x8 mk_frag(const unsigned short* u) {
    union { ushort8 uu; bf16x8 v; } c;
#pragma unroll
    for (int j = 0; j < 8; ++j) c.uu[j] = u[j];
    return c.v;
}

__global__ void init_out(const float* __restrict__ h, const float* __restrict__ x,
                         float* __restrict__ out) {
    int i = blockIdx.x * 256 + threadIdx.x;
    if (i < NH) out[i] = h[i];
    else if (i < NH + NX) out[i] = x[i - NH];
}

__global__ void prep_h(const float* __restrict__ h, unsigned short* __restrict__ hbf) {
    int i = (blockIdx.x * 256 + threadIdx.x) * 4;
    if (i < NH) {
        float4 v = *(const float4*)(h + i);
        ushort4v u = { f2bf(v.x), f2bf(v.y), f2bf(v.z), f2bf(v.w) };
        *(ushort4v*)(hbf + i) = u;
    }
}

// Wn1'[k][n] = k<128 ? Wn1[k][n] : sum_j We2[k-128][j]*Wn1[128+j][n]
// bn1'[n] = bn1[n] + sum_j be2[j]*Wn1[128+j][n]   (same for c path)
__global__ void prep_w(const float* __restrict__ We2, const float* __restrict__ be2,
                       const float* __restrict__ Wn1, const float* __restrict__ bn1,
                       const float* __restrict__ Wc1, const float* __restrict__ bc1,
                       unsigned short* __restrict__ wn1p, unsigned short* __restrict__ wc1p,
                       float* __restrict__ bn1p, float* __restrict__ bc1p) {
    int idx = blockIdx.x * 256 + threadIdx.x;
    if (idx >= 160 * 128) return;
    int k = idx >> 7, n = idx & 127;
    float vn, vc;
    if (k < 128) {
        vn = Wn1[k * HDIM + n];
        vc = Wc1[k * HDIM + n];
    } else {
        int i = k - 128;
        float sn = 0.0f, sc = 0.0f;
        for (int j = 0; j < 32; ++j) {
            float w = We2[i * 32 + j];
            sn += w * Wn1[(128 + j) * HDIM + n];
            sc += w * Wc1[(128 + j) * HDIM + n];
        }
        vn = sn; vc = sc;
    }
    wn1p[idx] = f2bf(vn);
    wc1p[idx] = f2bf(vc);
    if (idx < 128) {
        float sn = bn1[idx], sc = bc1[idx];
        for (int j = 0; j < 32; ++j) {
            sn += be2[j] * Wn1[(128 + j) * HDIM + idx];
            sc += be2[j] * Wc1[(128 + j) * HDIM + idx];
        }
        bn1p[idx] = sn;
        bc1p[idx] = sc;
    }
}

// (256,2): ~256 reg/thread budget -> 96-VGPR weight frags + ~80 AGPR accs stay
// resident. (256,3) spilled weights to scratch: 1 GB/launch refetch. Keep 2.
__global__ __launch_bounds__(256, 2) void egnn_edges(
    const unsigned short* __restrict__ hbf, const float* __restrict__ x,
    const int* __restrict__ srcg, const int* __restrict__ dstg,
    const float* __restrict__ dist,
    const float* __restrict__ We1, const float* __restrict__ be1,
    const unsigned short* __restrict__ wn1p, const float* __restrict__ bn1p,
    const float* __restrict__ Wn2, const float* __restrict__ bn2,
    const unsigned short* __restrict__ wc1p, const float* __restrict__ bc1p,
    const float* __restrict__ Wc2,
    float* __restrict__ outh, float* __restrict__ outx) {

    __shared__ __align__(16) unsigned short mlds[64 * MSTRIDE];
    __shared__ __align__(16) unsigned short hl[64 * HSTRIDE];
    __shared__ int src_l[64];
    __shared__ int dst_l[64];
    __shared__ float dist_l[64];
    __shared__ float part_l[256];

    const int tid  = threadIdx.x;
    const int w    = tid >> 6;
    const int lane = tid & 63;
    const int l15  = lane & 15;
    const int quad = lane >> 4;

    // ---- one-time: B-fragments to registers ----
    bf16x8 wn1f[5][2], wc1f[5][2];
#pragma unroll
    for (int kc = 0; kc < 5; ++kc) {
#pragma unroll
        for (int nt = 0; nt < 2; ++nt) {
            unsigned short un[8], uc[8];
            const int n = w * 32 + l15 * 2 + nt;
#pragma unroll
            for (int j = 0; j < 8; ++j) {
                const int k = kc * 32 + quad * 8 + j;
                un[j] = wn1p[k * HDIM + n];
                uc[j] = wc1p[k * HDIM + n];
            }
            wn1f[kc][nt] = mk_frag(un);
            wc1f[kc][nt] = mk_frag(uc);
        }
    }
    bf16x8 wn2f[4];
#pragma unroll
    for (int kc = 0; kc < 4; ++kc) {
        unsigned short u[8];
        const int n = w * 16 + l15;
#pragma unroll
        for (int j = 0; j < 8; ++j) {
            const int k = kc * 32 + quad * 8 + j;
            u[j] = f2bf(Wn2[k * NDIM + n]);
        }
        wn2f[kc] = mk_frag(u);
    }
    const float biasN0 = bn1p[w * 32 + l15 * 2];
    const float biasN1 = bn1p[w * 32 + l15 * 2 + 1];
    const float biasC0 = bc1p[w * 32 + l15 * 2];
    const float biasC1 = bc1p[w * 32 + l15 * 2 + 1];
    const float bias2v = bn2[w * 16 + l15];
    const float wc2a = Wc2[w * 32 + l15 * 2];
    const float wc2b = Wc2[w * 32 + l15 * 2 + 1];

    for (int tile = blockIdx.x; tile < NTILES; tile += gridDim.x) {
        __syncthreads();

        if (tid < 64) {
            const int e = tile * 64 + tid;
            src_l[tid] = srcg[e];
            dst_l[tid] = dstg[e];
            dist_l[tid] = dist[e];
        }
        __syncthreads();

        // ---- stage m_input = [h_src(64) | h_dst(64) | s(32)] bf16 ----
        {
            const int c8 = tid & 7, sub = tid >> 3;
#pragma unroll
            for (int it = 0; it < 2; ++it) {
                const int el = sub + it * 32;
                const ushort8 hs = *(const ushort8*)(hbf + (size_t)src_l[el] * NDIM + c8 * 8);
                const ushort8 hd = *(const ushort8*)(hbf + (size_t)dst_l[el] * NDIM + c8 * 8);
                *(ushort8*)&mlds[el * MSTRIDE + c8 * 8] = hs;
                *(ushort8*)&mlds[el * MSTRIDE + 64 + c8 * 8] = hd;
            }
        }
        // s = silu(d*We1 + be1), 8 vals/thread
        {
            const float dv = dist_l[lane];
            ushort8 su;
#pragma unroll
            for (int j = 0; j < 8; ++j) {
                const int k = w * 8 + j;
                su[j] = f2bf(silu(fmaf(dv, We1[k], be1[k])));
            }
            *(ushort8*)&mlds[lane * MSTRIDE + 128 + w * 8] = su;
        }
        __syncthreads();

        // ---- GEMM1: [64x160] @ {Wn1', Wc1'} ----
        f32x4 accN[4][2], accC[4][2];
#pragma unroll
        for (int mt = 0; mt < 4; ++mt) {
            accN[mt][0] = (f32x4){biasN0, biasN0, biasN0, biasN0};
            accN[mt][1] = (f32x4){biasN1, biasN1, biasN1, biasN1};
            accC[mt][0] = (f32x4){biasC0, biasC0, biasC0, biasC0};
            accC[mt][1] = (f32x4){biasC1, biasC1, biasC1, biasC1};
        }
#pragma unroll
        for (int kc = 0; kc < 5; ++kc) {
            bf16x8 af[4];
#pragma unroll
            for (int mt = 0; mt < 4; ++mt)
                af[mt] = ld_frag(&mlds[(mt * 16 + l15) * MSTRIDE + kc * 32 + quad * 8]);
#pragma unroll
            for (int mt = 0; mt < 4; ++mt) {
#pragma unroll
                for (int nt = 0; nt < 2; ++nt) {
                    accN[mt][nt] = __builtin_amdgcn_mfma_f32_16x16x32_bf16(
                        af[mt], wn1f[kc][nt], accN[mt][nt], 0, 0, 0);
                    accC[mt][nt] = __builtin_amdgcn_mfma_f32_16x16x32_bf16(
                        af[mt], wc1f[kc][nt], accC[mt][nt], 0, 0, 0);
                }
            }
        }

        // ---- node path: silu -> paired b32 writes (A-layout) ----
#pragma unroll
        for (int mt = 0; mt < 4; ++mt) {
#pragma unroll
            for (int r = 0; r < 4; ++r) {
                const int row = mt * 16 + quad * 4 + r;
                *(unsigned int*)&hl[row * HSTRIDE + w * 32 + l15 * 2] =
                    pk2bf(silu(accN[mt][0][r]), silu(accN[mt][1][r]));
            }
        }
        __syncthreads();

        // ---- GEMM2 node + atomic scatter ----
        f32x4 acc2[4];
#pragma unroll
        for (int mt = 0; mt < 4; ++mt) acc2[mt] = (f32x4){bias2v, bias2v, bias2v, bias2v};
#pragma unroll
        for (int kc = 0; kc < 4; ++kc) {
#pragma unroll
            for (int mt = 0; mt < 4; ++mt) {
                bf16x8 a2 = ld_frag(&hl[(mt * 16 + l15) * HSTRIDE + kc * 32 + quad * 8]);
                acc2[mt] = __builtin_amdgcn_mfma_f32_16x16x32_bf16(a2, wn2f[kc], acc2[mt], 0, 0, 0);
            }
        }
#pragma unroll
        for (int mt = 0; mt < 4; ++mt) {
#pragma unroll
            for (int r = 0; r < 4; ++r) {
                const int el = mt * 16 + quad * 4 + r;
                atomicAdd(outh + (size_t)dst_l[el] * NDIM + w * 16 + l15, acc2[mt][r]);
            }
        }

        // ---- coord path: in-register silu*Wc2 + shfl_xor fold ----
        {
            float vals[16];
#pragma unroll
            for (int mt = 0; mt < 4; ++mt)
#pragma unroll
                for (int r = 0; r < 4; ++r)
                    vals[mt * 4 + r] = silu(accC[mt][0][r]) * wc2a +
                                       silu(accC[mt][1][r]) * wc2b;
#pragma unroll
            for (int m = 8; m >= 1; m >>= 1) {
                const bool up = (l15 & m) != 0;
#pragma unroll
                for (int j = 0; j < 8; ++j) {
                    if (j < m) {
                        float send = up ? vals[j] : vals[j + m];
                        float recv = __shfl_xor(send, m, 64);
                        vals[j] = (up ? vals[j + m] : vals[j]) + recv;
                    }
                }
            }
            const int edge = ((l15 >> 2) << 4) + (quad << 2) + (l15 & 3);
            part_l[w * 64 + edge] = vals[0];
        }
        __syncthreads();

        if (tid < 64) {
            const float cw = part_l[tid] + part_l[64 + tid] + part_l[128 + tid] + part_l[192 + tid];
            const int sn = src_l[tid], dn = dst_l[tid];
            const float dx = x[sn * 3 + 0] - x[dn * 3 + 0];
            const float dy = x[sn * 3 + 1] - x[dn * 3 + 1];
            const float dz = x[sn * 3 + 2] - x[dn * 3 + 2];
            float len = sqrtf(dx * dx + dy * dy + dz * dz);
            len = fmaxf(len, 1e-8f);
            const float f = cw / len;
            atomicAdd(outx + (size_t)dn * 3 + 0, f * dx);
            atomicAdd(outx + (size_t)dn * 3 + 1, f * dy);
            atomicAdd(outx + (size_t)dn * 3 + 2, f * dz);
        }
    }
}

extern "C" void kernel_launch(void* const* d_in, const int* in_sizes, int n_in,
                              void* d_out, int out_size, void* d_ws, size_t ws_size,
                              hipStream_t stream) {
    const float* h    = (const float*)d_in[0];
    const float* x    = (const float*)d_in[1];
    const int*   ei   = (const int*)d_in[2];
    const float* dist = (const float*)d_in[3];
    const float* We1  = (const float*)d_in[4];
    const float* be1  = (const float*)d_in[5];
    const float* We2  = (const float*)d_in[6];
    const float* be2  = (const float*)d_in[7];
    const float* Wn1  = (const float*)d_in[8];
    const float* bn1  = (const float*)d_in[9];
    const float* Wn2  = (const float*)d_in[10];
    const float* bn2  = (const float*)d_in[11];
    const float* Wc1  = (const float*)d_in[12];
    const float* bc1  = (const float*)d_in[13];
    const float* Wc2  = (const float*)d_in[14];

    unsigned short* hbf  = (unsigned short*)((char*)d_ws + WS_HBF);
    unsigned short* wn1p = (unsigned short*)((char*)d_ws + WS_WN1P);
    unsigned short* wc1p = (unsigned short*)((char*)d_ws + WS_WC1P);
    float* bn1p = (float*)((char*)d_ws + WS_BN1P);
    float* bc1p = (float*)((char*)d_ws + WS_BC1P);

    float* outh = (float*)d_out;
    float* outx = outh + (size_t)NH;

    prep_h<<<(NH / 4 + 255) / 256, 256, 0, stream>>>(h, hbf);
    prep_w<<<(160 * 128 + 255) / 256, 256, 0, stream>>>(We2, be2, Wn1, bn1, Wc1, bc1,
                                                        wn1p, wc1p, bn1p, bc1p);
    init_out<<<(NH + NX + 255) / 256, 256, 0, stream>>>(h, x, (float*)d_out);
    egnn_edges<<<512, 256, 0, stream>>>(hbf, x, ei, ei + NE, dist,
                                        We1, be1, wn1p, bn1p,
                                        Wn2, bn2, wc1p, bc1p, Wc2,
                                        outh, outx);
}